// Round 4
// baseline (117.493 us; speedup 1.0000x reference)
//
#include <hip/hip_runtime.h>
#include <hip/hip_bf16.h>

// ContrastiveLoss (SupCon-style), N=4096 rows, K=256 dim, TEMP=0.5.
// loss = mean over same-label off-diag pairs of [log(neg_i + e_ij) - t2_ij],
//   t2_ij = 2*sim_ij, e_ij = exp(t2_ij), neg_i = sum_{lab_j != lab_i} e_ij.
// e_ij <= e^2 ~ 7.4, neg_i >= ~550  ->  per-pair log expands to per-row sums:
//   log(neg_i + e) = log(neg_i) + e/neg_i - e^2/(2 neg_i^2) + O(8e-6)
// so the MFMA pass only accumulates 5 per-row scalars:
//   neg, pexp=S e, pexp2=S e^2, pt2=S t2, pcnt   (S over pos pairs).
//
// R4: sim is SYMMETRIC -> compute only upper-triangle 16x16 tile-pairs
// (32896 of 65536) and scatter each element to BOTH row-i stats (shuffle
// reduce over cols) and row-j stats (per-block LDS col accumulators,
// ds_add_f32, flushed once per block). Mask j>i is exact on diagonal tiles.
// Tasks: wave = (istrip, 16-col tile group of its 64-col jseg J);
// istrip in [0, 4J+4) -> per-jseg tasks = 4J+4 (div by 4: block never
// straddles jsegs). blocks before J = J(J+1)/2, inverted via sqrt+fixup.
//
// pk layout per 16-row tile (4096 shorts): idx = c*512 + quad*128 + r16*8 + j
//   (row = r16, k = quad*8 + c*32 + j) == MFMA A/B fragment order, so every
// frag load is one contiguous 1KB wave segment.  [R3, validated -2.3x]
//
// ws: [0,2MB) packed bf16; [2MB,+80KB) stats 5 x 4096 f32.

#define N_ROWS 4096
#define K_DIM  256

typedef __attribute__((ext_vector_type(8))) short short8;     // 8 x bf16
typedef __attribute__((ext_vector_type(4))) float float4v;    // MFMA C/D
typedef __attribute__((ext_vector_type(4))) float f4;

#define PK_OFF    0
#define STATS_OFF (N_ROWS * K_DIM * 2)   // 2 MB

// ---------------------------------------------------------------------------
// K1: block = one 16-row tile. Coalesced float4 global loads -> LDS,
// per-row norms via 16-lane shuffle groups, fully-coalesced 32B/thread
// packed-fragment stores. Also zeroes the stat arrays (80 floats/block).
__global__ void normalize_kernel(const float* __restrict__ emb,
                                 short* __restrict__ pk,
                                 float* __restrict__ stats) {
    int tile = blockIdx.x, t = threadIdx.x;
    __shared__ float lds[16 * 256];
    __shared__ float sc[16];
    const f4* src = (const f4*)(emb + tile * 16 * 256);
    f4* dst4 = (f4*)lds;
    #pragma unroll
    for (int it = 0; it < 4; ++it) dst4[t + 256 * it] = src[t + 256 * it];
    __syncthreads();
    int wave = t >> 6, lane = t & 63;
    int row = wave * 4 + (lane >> 4);          // 4 rows per wave
    float s = 0.f;
    #pragma unroll
    for (int m = 0; m < 16; ++m) {             // lane sums k = (lane&15)+16m
        float x = lds[row * 256 + (lane & 15) + 16 * m];
        s += x * x;
    }
    s += __shfl_xor(s, 1); s += __shfl_xor(s, 2);
    s += __shfl_xor(s, 4); s += __shfl_xor(s, 8);
    float scale = 1.0f / fmaxf(sqrtf(s), 1e-12f);
    if ((lane & 15) == 0) sc[row] = scale;
    __syncthreads();
    // pack: thread t writes 16 contiguous shorts (32 B) of the 8 KB tile
    short out[16];
    #pragma unroll
    for (int u = 0; u < 16; ++u) {
        int p = t * 16 + u;                    // packed idx within tile
        int j = p & 7, r16 = (p >> 3) & 15, quad = (p >> 7) & 3, c = p >> 9;
        int k = quad * 8 + c * 32 + j;
        float v = lds[r16 * 256 + k] * sc[r16];
        __hip_bfloat16 b = __float2bfloat16(v);
        out[u] = *(short*)&b;
    }
    short* dst = pk + tile * 4096 + t * 16;
    *(short8*)dst = *(short8*)out;
    *(short8*)(dst + 8) = *(short8*)(out + 8);
    if (t < 80) stats[tile * 80 + t] = 0.0f;   // 256*80 = 20480 = 5*4096
}

// ---------------------------------------------------------------------------
// K2: upper-triangle fused sim/exp/stats pass. Grid: 2080 blocks x 4 waves.
// Wave = 16 rows x up-to-64 cols (4 16-col tiles of jseg J).
// C/D: col = lane&15, row = (lane>>4)*4 + reg  [learn_hip m89/m91].
__global__ void negsum_kernel(const short* __restrict__ pk,
                              const int* __restrict__ labels,
                              float* __restrict__ stats) {
    int w = threadIdx.x >> 6, lane = threadIdx.x & 63;
    int row16 = lane & 15, quad = lane >> 4;
    int b = blockIdx.x;
    // invert triangular block index: largest J with J(J+1)/2 <= b
    int J = (int)((sqrtf(8.0f * (float)b + 1.0f) - 1.0f) * 0.5f);
    while ((J + 1) * (J + 2) / 2 <= b) ++J;
    while (J * (J + 1) / 2 > b) --J;
    int istrip = 4 * (b - J * (J + 1) / 2) + w;   // [0, 4J+4)
    int i0 = istrip * 16;

    __shared__ float cst[5 * 64];                  // col-side stats for jseg J
    for (int f = threadIdx.x; f < 5 * 64; f += 256) cst[f] = 0.f;
    __syncthreads();

    short8 afrag[8];
    {
        const short* ap = pk + (istrip << 12) + lane * 8;
        #pragma unroll
        for (int c = 0; c < 8; ++c)
            afrag[c] = *reinterpret_cast<const short8*>(ap + (c << 9));
    }
    int irow[4], labi[4];
    #pragma unroll
    for (int r = 0; r < 4; ++r) {
        irow[r] = i0 + quad * 4 + r;
        labi[r] = labels[irow[r]];
    }

    float nacc[4] = {0,0,0,0}, pe[4] = {0,0,0,0}, pe2[4] = {0,0,0,0};
    float ptt[4] = {0,0,0,0}, pc[4] = {0,0,0,0};

    int jt0 = istrip - 4 * J; if (jt0 < 0) jt0 = 0;   // skip tiles below diag
    for (int jt = jt0; jt < 4; ++jt) {
        int jtile = 4 * J + jt;
        const short* bp = pk + (jtile << 12) + lane * 8;
        float4v accf = {0.f, 0.f, 0.f, 0.f};
        #pragma unroll
        for (int c = 0; c < 8; ++c) {
            short8 bfrag = *reinterpret_cast<const short8*>(bp + (c << 9));
            accf = __builtin_amdgcn_mfma_f32_16x16x32_bf16(afrag[c], bfrag, accf, 0, 0, 0);
        }
        int j = jtile * 16 + row16;
        int labj = labels[j];
        float cneg = 0.f, cpe = 0.f, cpe2 = 0.f, cptt = 0.f, cpc = 0.f;
        #pragma unroll
        for (int r = 0; r < 4; ++r) {
            float t2 = 2.0f * accf[r];
            float e  = __expf(t2);
            bool keep = (j > irow[r]);          // exact diag/triangle mask
            bool same = (labj == labi[r]);
            float ek = keep ? e : 0.f;
            float m  = (same && keep) ? 1.f : 0.f;
            float nk = same ? 0.f : ek;
            float px = m * e, px2 = m * e * e, pt = m * t2;
            nacc[r] += nk;  cneg += nk;
            pe[r]   += px;  cpe  += px;
            pe2[r]  += px2; cpe2 += px2;
            ptt[r]  += pt;  cptt += pt;
            pc[r]   += m;   cpc  += m;
        }
        int cl = jt * 16 + row16;               // local col within jseg
        atomicAdd(&cst[0 * 64 + cl], cneg);     // 4-way same-addr, HW-serialized
        if (__any(cpc > 0.f)) {
            atomicAdd(&cst[1 * 64 + cl], cpe);
            atomicAdd(&cst[2 * 64 + cl], cpe2);
            atomicAdd(&cst[3 * 64 + cl], cptt);
            atomicAdd(&cst[4 * 64 + cl], cpc);
        }
    }

    // row-side: reduce over the 16 col-lanes of each quad, atomics from 4 lanes
    float* neg = stats;
    #pragma unroll
    for (int r = 0; r < 4; ++r) {
        float v0 = nacc[r], v1 = pe[r], v2 = pe2[r], v3 = ptt[r], v4 = pc[r];
        #pragma unroll
        for (int m = 1; m < 16; m <<= 1) {
            v0 += __shfl_xor(v0, m); v1 += __shfl_xor(v1, m);
            v2 += __shfl_xor(v2, m); v3 += __shfl_xor(v3, m);
            v4 += __shfl_xor(v4, m);
        }
        if (row16 == 0) {
            atomicAdd(&neg[irow[r]], v0);
            if (v4 > 0.0f) {
                atomicAdd(&stats[1 * N_ROWS + irow[r]], v1);
                atomicAdd(&stats[2 * N_ROWS + irow[r]], v2);
                atomicAdd(&stats[3 * N_ROWS + irow[r]], v3);
                atomicAdd(&stats[4 * N_ROWS + irow[r]], v4);
            }
        }
    }

    // col-side flush: one pass per block
    __syncthreads();
    int jbase = J * 64;
    for (int f = threadIdx.x; f < 5 * 64; f += 256) {
        int arr = f >> 6, c = f & 63;
        float v = cst[f];
        if (v != 0.f) atomicAdd(&stats[arr * N_ROWS + jbase + c], v);
    }
}

// ---------------------------------------------------------------------------
// K3: single-block finalize: per-row closed form, block reduce, write scalar.
__global__ void finalize_kernel(const float* __restrict__ stats,
                                float* __restrict__ out) {
    const float* neg   = stats;
    const float* pexp  = stats + N_ROWS;
    const float* pexp2 = stats + 2 * N_ROWS;
    const float* pt2   = stats + 3 * N_ROWS;
    const float* pcnt  = stats + 4 * N_ROWS;
    float lsum = 0.f, csum = 0.f;
    for (int i = threadIdx.x; i < N_ROWS; i += 256) {
        float c = pcnt[i];
        if (c > 0.f) {
            float n = neg[i];
            float invn = 1.0f / n;
            lsum += c * logf(n) + pexp[i] * invn
                    - 0.5f * pexp2[i] * invn * invn - pt2[i];
            csum += c;
        }
    }
    #pragma unroll
    for (int off = 32; off > 0; off >>= 1) {
        lsum += __shfl_down(lsum, off, 64);
        csum += __shfl_down(csum, off, 64);
    }
    __shared__ float sl[4], sc2[4];
    int wave = threadIdx.x >> 6, lane = threadIdx.x & 63;
    if (lane == 0) { sl[wave] = lsum; sc2[wave] = csum; }
    __syncthreads();
    if (threadIdx.x == 0)
        out[0] = (sl[0] + sl[1] + sl[2] + sl[3]) / (sc2[0] + sc2[1] + sc2[2] + sc2[3]);
}

// ---------------------------------------------------------------------------
extern "C" void kernel_launch(void* const* d_in, const int* in_sizes, int n_in,
                              void* d_out, int out_size, void* d_ws, size_t ws_size,
                              hipStream_t stream) {
    const float* emb    = (const float*)d_in[0];
    const int*   labels = (const int*)d_in[1];
    float* out = (float*)d_out;
    char*  ws  = (char*)d_ws;

    short* pk    = (short*)(ws + PK_OFF);
    float* stats = (float*)(ws + STATS_OFF);

    normalize_kernel<<<N_ROWS / 16, 256, 0, stream>>>(emb, pk, stats);
    negsum_kernel<<<2080, 256, 0, stream>>>(pk, labels, stats);
    finalize_kernel<<<1, 256, 0, stream>>>(stats, out);
}

// Round 5
// 94.434 us; speedup vs baseline: 1.2442x; 1.2442x over previous
//
#include <hip/hip_runtime.h>
#include <hip/hip_bf16.h>

// ContrastiveLoss (SupCon-style), N=4096 rows, K=256 dim, TEMP=0.5.
// loss = mean over same-label off-diag pairs of [log(neg_i + e_ij) - t2_ij],
//   t2_ij = 2*sim_ij, e_ij = exp(t2_ij), neg_i = sum_{lab_j != lab_i} e_ij.
// e_ij <= e^2 ~ 7.4, neg_i >= ~550  ->  per-pair log expands to per-row sums:
//   log(neg_i + e) = log(neg_i) + e/neg_i - e^2/(2 neg_i^2) + O(8e-6)
// Stats per row: neg (dense), pexp/pexp2/pt2/pcnt (pos pairs, 1/512 sparse).
//
// R5 (R4 symmetry REVERTED — LDS-atomic epilogue cost > halved work):
// R2-R4 showed all pipes <15% busy at 40-50us -> L2 request-rate/latency
// bound (each B wave-load = 16 L2 lines; ~9.4M line-req ~ 77% of ~307Greq/s).
// Fixes: (1) stage each jseg's B-tiles (64KB) in LDS once per 8-wave block;
// (2) 2 i-strips per wave -> one B ds_read feeds 2 independent MFMA chains;
// (3) sparse pos pairs via ballot-guarded direct global atomics; only neg
// gets the dense shuffle reduction (32 shuffles/wave vs R3's 80).
//
// pk layout per 16-row tile (4096 shorts): idx = c*512 + quad*128 + r16*8 + j
//   (row = r16, k = quad*8 + c*32 + j) == MFMA A/B fragment order, so every
// frag load is one contiguous 1KB wave segment.  [R3, validated]
//
// ws: [0,2MB) packed bf16; [2MB,+80KB) stats 5 x 4096 f32.

#define N_ROWS 4096
#define K_DIM  256

typedef __attribute__((ext_vector_type(8))) short short8;     // 8 x bf16
typedef __attribute__((ext_vector_type(4))) float float4v;    // MFMA C/D
typedef __attribute__((ext_vector_type(4))) float f4;

#define PK_OFF    0
#define STATS_OFF (N_ROWS * K_DIM * 2)   // 2 MB

// ---------------------------------------------------------------------------
// K1: block = one 16-row tile. Coalesced float4 loads -> LDS, per-row norms
// via 16-lane shuffle groups, coalesced 32B/thread packed-fragment stores.
// Also zeroes the stat arrays (80 floats/block x 256 blocks = 20480).
__global__ void normalize_kernel(const float* __restrict__ emb,
                                 short* __restrict__ pk,
                                 float* __restrict__ stats) {
    int tile = blockIdx.x, t = threadIdx.x;
    __shared__ float lds[16 * 256];
    __shared__ float sc[16];
    const f4* src = (const f4*)(emb + tile * 16 * 256);
    f4* dst4 = (f4*)lds;
    #pragma unroll
    for (int it = 0; it < 4; ++it) dst4[t + 256 * it] = src[t + 256 * it];
    __syncthreads();
    int wave = t >> 6, lane = t & 63;
    int row = wave * 4 + (lane >> 4);          // 4 rows per wave
    float s = 0.f;
    #pragma unroll
    for (int m = 0; m < 16; ++m) {             // lane sums k = (lane&15)+16m
        float x = lds[row * 256 + (lane & 15) + 16 * m];
        s += x * x;
    }
    s += __shfl_xor(s, 1); s += __shfl_xor(s, 2);
    s += __shfl_xor(s, 4); s += __shfl_xor(s, 8);
    float scale = 1.0f / fmaxf(sqrtf(s), 1e-12f);
    if ((lane & 15) == 0) sc[row] = scale;
    __syncthreads();
    short out[16];
    #pragma unroll
    for (int u = 0; u < 16; ++u) {
        int p = t * 16 + u;                    // packed idx within tile
        int j = p & 7, r16 = (p >> 3) & 15, quad = (p >> 7) & 3, c = p >> 9;
        int k = quad * 8 + c * 32 + j;
        float v = lds[r16 * 256 + k] * sc[r16];
        __hip_bfloat16 b = __float2bfloat16(v);
        out[u] = *(short*)&b;
    }
    short* dst = pk + tile * 4096 + t * 16;
    *(short8*)dst = *(short8*)out;
    *(short8*)(dst + 8) = *(short8*)(out + 8);
    if (t < 80) stats[tile * 80 + t] = 0.0f;
}

// ---------------------------------------------------------------------------
// K2: fused sim/exp/stats. Grid 512 blocks x 8 waves (512 thr).
// Block = 32 rows/wave-pair... : igroup (16 istrips = 256 rows) x jseg J
// (128 cols = 8 tiles, 64KB staged in LDS). Wave = 2 istrips x 8 tiles.
// C/D: col = lane&15, row = (lane>>4)*4 + reg  [learn_hip m89/m91].
__global__ __launch_bounds__(512, 4)
void negsum_kernel(const short* __restrict__ pk,
                   const int* __restrict__ labels,
                   float* __restrict__ stats) {
    __shared__ short bs[8 * 4096];             // 8 B-tiles, pk layout, 64 KB
    __shared__ int   labS[128];
    int t = threadIdx.x;
    int w = t >> 6, lane = t & 63;
    int row16 = lane & 15, quad = lane >> 4;
    int J = blockIdx.x & 31;                   // jseg
    int igroup = blockIdx.x >> 5;              // 0..15

    // ---- stage B-tiles (contiguous 64KB of pk) + col labels ----
    {
        const short8* src = (const short8*)(pk + J * 32768);
        short8* dst = (short8*)bs;
        #pragma unroll
        for (int it = 0; it < 8; ++it)
            dst[t + it * 512] = src[t + it * 512];
        if (t < 128) labS[t] = labels[J * 128 + t];
    }
    __syncthreads();

    // ---- A fragments for 2 i-strips (registers) ----
    short8 af[2][8];
    int istrip0 = igroup * 16 + w * 2;
    #pragma unroll
    for (int s = 0; s < 2; ++s) {
        const short* ap = pk + ((istrip0 + s) << 12) + lane * 8;
        #pragma unroll
        for (int c = 0; c < 8; ++c)
            af[s][c] = *(const short8*)(ap + (c << 9));
    }
    int irow[2][4], labi[2][4];
    #pragma unroll
    for (int s = 0; s < 2; ++s)
        #pragma unroll
        for (int r = 0; r < 4; ++r) {
            irow[s][r] = (istrip0 + s) * 16 + quad * 4 + r;
            labi[s][r] = labels[irow[s][r]];
        }

    float nacc[2][4] = {{0,0,0,0},{0,0,0,0}};

    for (int jt = 0; jt < 8; ++jt) {
        const short* bp = bs + (jt << 12) + lane * 8;
        float4v acc[2] = {{0.f,0.f,0.f,0.f},{0.f,0.f,0.f,0.f}};
        #pragma unroll
        for (int c = 0; c < 8; ++c) {
            short8 b = *(const short8*)(bp + (c << 9));   // ds_read_b128
            acc[0] = __builtin_amdgcn_mfma_f32_16x16x32_bf16(af[0][c], b, acc[0], 0, 0, 0);
            acc[1] = __builtin_amdgcn_mfma_f32_16x16x32_bf16(af[1][c], b, acc[1], 0, 0, 0);
        }
        int j    = J * 128 + jt * 16 + row16;  // this lane's global column
        int labj = labS[jt * 16 + row16];
        #pragma unroll
        for (int s = 0; s < 2; ++s) {
            #pragma unroll
            for (int r = 0; r < 4; ++r) {
                float t2 = 2.0f * acc[s][r];
                float e  = __expf(t2);
                bool same = (labj == labi[s][r]);
                nacc[s][r] += same ? 0.0f : e;
                bool p = same && (j != irow[s][r]);        // pos pair (sparse)
                if (__any(p)) {
                    if (p) {
                        atomicAdd(&stats[1 * N_ROWS + irow[s][r]], e);
                        atomicAdd(&stats[2 * N_ROWS + irow[s][r]], e * e);
                        atomicAdd(&stats[3 * N_ROWS + irow[s][r]], t2);
                        atomicAdd(&stats[4 * N_ROWS + irow[s][r]], 1.0f);
                    }
                }
            }
        }
    }

    // ---- neg: reduce over the 16 col-lanes of each quad, 4-lane atomics ----
    #pragma unroll
    for (int s = 0; s < 2; ++s)
        #pragma unroll
        for (int r = 0; r < 4; ++r) {
            float v = nacc[s][r];
            v += __shfl_xor(v, 1); v += __shfl_xor(v, 2);
            v += __shfl_xor(v, 4); v += __shfl_xor(v, 8);
            if (row16 == 0) atomicAdd(&stats[irow[s][r]], v);
        }
}

// ---------------------------------------------------------------------------
// K3: single-block finalize: per-row closed form, block reduce, write scalar.
__global__ void finalize_kernel(const float* __restrict__ stats,
                                float* __restrict__ out) {
    const float* neg   = stats;
    const float* pexp  = stats + N_ROWS;
    const float* pexp2 = stats + 2 * N_ROWS;
    const float* pt2   = stats + 3 * N_ROWS;
    const float* pcnt  = stats + 4 * N_ROWS;
    float lsum = 0.f, csum = 0.f;
    for (int i = threadIdx.x; i < N_ROWS; i += 256) {
        float c = pcnt[i];
        if (c > 0.f) {
            float n = neg[i];
            float invn = 1.0f / n;
            lsum += c * logf(n) + pexp[i] * invn
                    - 0.5f * pexp2[i] * invn * invn - pt2[i];
            csum += c;
        }
    }
    #pragma unroll
    for (int off = 32; off > 0; off >>= 1) {
        lsum += __shfl_down(lsum, off, 64);
        csum += __shfl_down(csum, off, 64);
    }
    __shared__ float sl[4], sc2[4];
    int wave = threadIdx.x >> 6, lane = threadIdx.x & 63;
    if (lane == 0) { sl[wave] = lsum; sc2[wave] = csum; }
    __syncthreads();
    if (threadIdx.x == 0)
        out[0] = (sl[0] + sl[1] + sl[2] + sl[3]) / (sc2[0] + sc2[1] + sc2[2] + sc2[3]);
}

// ---------------------------------------------------------------------------
extern "C" void kernel_launch(void* const* d_in, const int* in_sizes, int n_in,
                              void* d_out, int out_size, void* d_ws, size_t ws_size,
                              hipStream_t stream) {
    const float* emb    = (const float*)d_in[0];
    const int*   labels = (const int*)d_in[1];
    float* out = (float*)d_out;
    char*  ws  = (char*)d_ws;

    short* pk    = (short*)(ws + PK_OFF);
    float* stats = (float*)(ws + STATS_OFF);

    normalize_kernel<<<N_ROWS / 16, 256, 0, stream>>>(emb, pk, stats);
    negsum_kernel<<<512, 512, 0, stream>>>(pk, labels, stats);
    finalize_kernel<<<1, 256, 0, stream>>>(stats, out);
}

// Round 6
// 83.155 us; speedup vs baseline: 1.4129x; 1.1356x over previous
//
#include <hip/hip_runtime.h>
#include <hip/hip_bf16.h>

// ContrastiveLoss (SupCon-style), N=4096 rows, K=256 dim, TEMP=0.5.
// loss = mean over same-label off-diag pairs of [log(neg_i + e_ij) - t2_ij],
//   t2_ij = 2*sim_ij, e_ij = exp(t2_ij), neg_i = sum_{lab_j != lab_i} e_ij.
// e_ij <= e^2 ~ 7.4, neg_i >= ~550  ->  per-pair log expands to per-row sums:
//   log(neg_i + e) = log(neg_i) + e/neg_i - e^2/(2 neg_i^2) + O(8e-6)
// Per-row stats: neg, pexp, pexp2, pt2, pcnt.
//
// R6: R3-R5 all plateau 40-50us with EVERY pipe <15% busy; R5's WRITE_SIZE
// 28.6MB == ~500k lane-atomics x 64B write-through --> global atomics execute
// at the device-coherent memory-side point (per-XCD L2s non-coherent) and the
// wave's waitcnt stream entangles with their ~900cyc latency. HYPOTHESIS TEST:
// remove ALL in-loop global atomics. Pos stats accumulate in registers across
// jt (dense FMAs, no branch), one 16-lane shuffle reduce per wave, then PLAIN
// stores to contention-free partials P[5][J=32][row=4096] (each (J,row) slot
// written by exactly one block). rowreduce kernel sums 32 partials/row,
// computes closed-form per-row loss, 2 scalar atomics per block (16 blocks).
//
// pk layout per 16-row tile (4096 shorts): idx = c*512 + quad*128 + r16*8 + j
//   (row=r16, k=quad*8+c*32+j) == MFMA A/B fragment order -> every frag load
// is one contiguous 1KB wave segment. [R3, validated]
//
// ws: [0,2MB) pk bf16; [2MB,+2.62MB) partials; then acc[2].

#define N_ROWS 4096
#define K_DIM  256

typedef __attribute__((ext_vector_type(8))) short short8;     // 8 x bf16
typedef __attribute__((ext_vector_type(4))) float float4v;    // MFMA C/D
typedef __attribute__((ext_vector_type(4))) float f4;

#define PK_OFF    0
#define PART_OFF  (N_ROWS * K_DIM * 2)                 // 2 MB
#define PART_SZ   (5 * 32 * N_ROWS)                    // floats
#define ACC_OFF   (PART_OFF + PART_SZ * 4)

// ---------------------------------------------------------------------------
// K1: block = one 16-row tile. Coalesced float4 loads -> LDS, per-row norms
// via 16-lane shuffle groups, coalesced 32B/thread packed-fragment stores.
__global__ void normalize_kernel(const float* __restrict__ emb,
                                 short* __restrict__ pk,
                                 float* __restrict__ acc) {
    int tile = blockIdx.x, t = threadIdx.x;
    __shared__ float lds[16 * 256];
    __shared__ float sc[16];
    const f4* src = (const f4*)(emb + tile * 16 * 256);
    f4* dst4 = (f4*)lds;
    #pragma unroll
    for (int it = 0; it < 4; ++it) dst4[t + 256 * it] = src[t + 256 * it];
    __syncthreads();
    int wave = t >> 6, lane = t & 63;
    int row = wave * 4 + (lane >> 4);          // 4 rows per wave
    float s = 0.f;
    #pragma unroll
    for (int m = 0; m < 16; ++m) {
        float x = lds[row * 256 + (lane & 15) + 16 * m];
        s += x * x;
    }
    s += __shfl_xor(s, 1); s += __shfl_xor(s, 2);
    s += __shfl_xor(s, 4); s += __shfl_xor(s, 8);
    float scale = 1.0f / fmaxf(sqrtf(s), 1e-12f);
    if ((lane & 15) == 0) sc[row] = scale;
    __syncthreads();
    short out[16];
    #pragma unroll
    for (int u = 0; u < 16; ++u) {
        int p = t * 16 + u;
        int j = p & 7, r16 = (p >> 3) & 15, quad = (p >> 7) & 3, c = p >> 9;
        int k = quad * 8 + c * 32 + j;
        float v = lds[r16 * 256 + k] * sc[r16];
        __hip_bfloat16 b = __float2bfloat16(v);
        out[u] = *(short*)&b;
    }
    short* dst = pk + tile * 4096 + t * 16;
    *(short8*)dst = *(short8*)out;
    *(short8*)(dst + 8) = *(short8*)(out + 8);
    if (tile == 0 && t < 2) acc[t] = 0.0f;     // zero the scalar accumulators
}

// ---------------------------------------------------------------------------
// K2: fused sim/exp/stats, ATOMIC-FREE. Grid 512 blocks x 8 waves.
// Block = (igroup: 16 istrips = 256 rows) x (jseg J: 128 cols staged in LDS).
// Wave = 2 istrips x 8 col-tiles. All 5 stats accumulate in registers; one
// shuffle reduce at the end; plain stores to part[st][J][row].
// C/D: col = lane&15, row = (lane>>4)*4 + reg  [learn_hip m89/m91].
__global__ __launch_bounds__(512, 4)
void negsum_kernel(const short* __restrict__ pk,
                   const int* __restrict__ labels,
                   float* __restrict__ part) {
    __shared__ short bs[8 * 4096];             // 8 B-tiles, pk layout, 64 KB
    __shared__ int   labS[128];
    int t = threadIdx.x;
    int w = t >> 6, lane = t & 63;
    int row16 = lane & 15, quad = lane >> 4;
    int J = blockIdx.x & 31;
    int igroup = blockIdx.x >> 5;

    {
        const short8* src = (const short8*)(pk + J * 32768);
        short8* dst = (short8*)bs;
        #pragma unroll
        for (int it = 0; it < 8; ++it)
            dst[t + it * 512] = src[t + it * 512];
        if (t < 128) labS[t] = labels[J * 128 + t];
    }
    __syncthreads();

    short8 af[2][8];
    int istrip0 = igroup * 16 + w * 2;
    #pragma unroll
    for (int s = 0; s < 2; ++s) {
        const short* ap = pk + ((istrip0 + s) << 12) + lane * 8;
        #pragma unroll
        for (int c = 0; c < 8; ++c)
            af[s][c] = *(const short8*)(ap + (c << 9));
    }
    int irow[2][4], labi[2][4];
    #pragma unroll
    for (int s = 0; s < 2; ++s)
        #pragma unroll
        for (int r = 0; r < 4; ++r) {
            irow[s][r] = (istrip0 + s) * 16 + quad * 4 + r;
            labi[s][r] = labels[irow[s][r]];
        }

    float nacc[2][4] = {{0,0,0,0},{0,0,0,0}};
    float pe[2][4]   = {{0,0,0,0},{0,0,0,0}};
    float pe2[2][4]  = {{0,0,0,0},{0,0,0,0}};
    float ptt[2][4]  = {{0,0,0,0},{0,0,0,0}};
    float pc[2][4]   = {{0,0,0,0},{0,0,0,0}};

    for (int jt = 0; jt < 8; ++jt) {
        const short* bp = bs + (jt << 12) + lane * 8;
        float4v acc[2] = {{0.f,0.f,0.f,0.f},{0.f,0.f,0.f,0.f}};
        #pragma unroll
        for (int c = 0; c < 8; ++c) {
            short8 b = *(const short8*)(bp + (c << 9));   // ds_read_b128
            acc[0] = __builtin_amdgcn_mfma_f32_16x16x32_bf16(af[0][c], b, acc[0], 0, 0, 0);
            acc[1] = __builtin_amdgcn_mfma_f32_16x16x32_bf16(af[1][c], b, acc[1], 0, 0, 0);
        }
        int j    = J * 128 + jt * 16 + row16;  // this lane's global column
        int labj = labS[jt * 16 + row16];
        #pragma unroll
        for (int s = 0; s < 2; ++s) {
            #pragma unroll
            for (int r = 0; r < 4; ++r) {
                float t2 = 2.0f * acc[s][r];
                float e  = __expf(t2);
                bool same = (labj == labi[s][r]);
                bool p    = same && (j != irow[s][r]);
                float m   = p ? 1.0f : 0.0f;
                nacc[s][r] += same ? 0.0f : e;
                pe[s][r]   = fmaf(m, e,      pe[s][r]);
                pe2[s][r]  = fmaf(m, e * e,  pe2[s][r]);
                ptt[s][r]  = fmaf(m, t2,     ptt[s][r]);
                pc[s][r]  += m;
            }
        }
    }

    // 16-lane (col) reduce per (s,r); lanes row16==0 hold rows quad*4+r.
    // Plain contention-free stores: part[st*131072 + J*4096 + row].
    #pragma unroll
    for (int s = 0; s < 2; ++s)
        #pragma unroll
        for (int r = 0; r < 4; ++r) {
            float v0 = nacc[s][r], v1 = pe[s][r], v2 = pe2[s][r];
            float v3 = ptt[s][r],  v4 = pc[s][r];
            #pragma unroll
            for (int m = 1; m < 16; m <<= 1) {
                v0 += __shfl_xor(v0, m); v1 += __shfl_xor(v1, m);
                v2 += __shfl_xor(v2, m); v3 += __shfl_xor(v3, m);
                v4 += __shfl_xor(v4, m);
            }
            if (row16 == 0) {
                int idx = J * N_ROWS + irow[s][r];
                part[0 * 32 * N_ROWS + idx] = v0;
                part[1 * 32 * N_ROWS + idx] = v1;
                part[2 * 32 * N_ROWS + idx] = v2;
                part[3 * 32 * N_ROWS + idx] = v3;
                part[4 * 32 * N_ROWS + idx] = v4;
            }
        }
}

// ---------------------------------------------------------------------------
// K3: sum the 32 J-partials per row, closed-form per-row loss, block reduce,
// 2 scalar atomics per block. Grid 16 x 256 (thread = one row).
__global__ void rowreduce_kernel(const float* __restrict__ part,
                                 float* __restrict__ acc) {
    int i = blockIdx.x * 256 + threadIdx.x;
    float n = 0.f, e1 = 0.f, e2 = 0.f, tt = 0.f, c = 0.f;
    for (int J = 0; J < 32; ++J) {
        int idx = J * N_ROWS + i;
        n  += part[0 * 32 * N_ROWS + idx];
        e1 += part[1 * 32 * N_ROWS + idx];
        e2 += part[2 * 32 * N_ROWS + idx];
        tt += part[3 * 32 * N_ROWS + idx];
        c  += part[4 * 32 * N_ROWS + idx];
    }
    float lsum = 0.f;
    if (c > 0.f) {
        float invn = 1.0f / n;
        lsum = c * logf(n) + e1 * invn - 0.5f * e2 * invn * invn - tt;
    }
    #pragma unroll
    for (int off = 32; off > 0; off >>= 1) {
        lsum += __shfl_down(lsum, off, 64);
        c    += __shfl_down(c,    off, 64);
    }
    __shared__ float sl[4], sc2[4];
    int wave = threadIdx.x >> 6, lane = threadIdx.x & 63;
    if (lane == 0) { sl[wave] = lsum; sc2[wave] = c; }
    __syncthreads();
    if (threadIdx.x == 0) {
        atomicAdd(&acc[0], sl[0] + sl[1] + sl[2] + sl[3]);
        atomicAdd(&acc[1], sc2[0] + sc2[1] + sc2[2] + sc2[3]);
    }
}

// ---------------------------------------------------------------------------
__global__ void div_kernel(const float* __restrict__ acc, float* __restrict__ out) {
    if (threadIdx.x == 0) out[0] = acc[0] / acc[1];
}

// ---------------------------------------------------------------------------
extern "C" void kernel_launch(void* const* d_in, const int* in_sizes, int n_in,
                              void* d_out, int out_size, void* d_ws, size_t ws_size,
                              hipStream_t stream) {
    const float* emb    = (const float*)d_in[0];
    const int*   labels = (const int*)d_in[1];
    float* out = (float*)d_out;
    char*  ws  = (char*)d_ws;

    short* pk   = (short*)(ws + PK_OFF);
    float* part = (float*)(ws + PART_OFF);
    float* acc  = (float*)(ws + ACC_OFF);

    normalize_kernel<<<N_ROWS / 16, 256, 0, stream>>>(emb, pk, acc);
    negsum_kernel<<<512, 512, 0, stream>>>(pk, labels, part);
    rowreduce_kernel<<<16, 256, 0, stream>>>(part, acc);
    div_kernel<<<1, 64, 0, stream>>>(acc, out);
}